// Round 11
// baseline (494.323 us; speedup 1.0000x reference)
//
#include <hip/hip_runtime.h>

// SAGE_Net: 2-layer GraphSAGE, N=100k, E=1.6M, 128->128->64, fp32.
// R20: direct CSR build. R19's accounting (top-5 displacement bound) showed
// agg_out < 98us in every iteration -> R18's 134us residual was agg_out
// (~90) + ~40us dispatch overhead; agg_out is latency-floored (3 layouts,
// same time). Remaining attackable: CSR build (4 kernels + 25.6MB eb
// round-trip). New: k_deg (atomics, L2-resident 400KB) -> k_scan (1-block
// 1024-thr two-pass int4 scan) -> k_scatter (atomicAdd(cur[dst]) -> col).
// One fewer dispatch, no eb. Column order within node = atomic order
// (bfinal was already atomic-ordered -> same tolerance class).
// k_fused / k_agg_out byte-identical to R19 (99us / <98us measured).

typedef unsigned int uint32;
typedef short bf16x8 __attribute__((ext_vector_type(8)));
typedef float f32x16 __attribute__((ext_vector_type(16)));
typedef float f32x2 __attribute__((ext_vector_type(2)));

#define PSTR 264  // LDS plane stride in shorts (32*8 + 8 pad; 528B)

__device__ __forceinline__ uint32 pack_bf16_rne(float a, float b) {
    uint32 ua = __float_as_uint(a);
    uint32 ub = __float_as_uint(b);
    uint32 ra = (ua + 0x7fffu + ((ua >> 16) & 1u)) >> 16;
    uint32 rb = (ub + 0x7fffu + ((ub >> 16) & 1u)) >> 16;
    return ra | (rb << 16);
}
__device__ __forceinline__ float bf_lo(uint32 v) { return __uint_as_float(v << 16); }
__device__ __forceinline__ float bf_hi(uint32 v) { return __uint_as_float(v & 0xffff0000u); }

__device__ __forceinline__ short rne16(float v, float* back) {
    uint32 u = __float_as_uint(v);
    uint32 r = (u + 0x7fffu + ((u >> 16) & 1u)) >> 16;
    *back = __uint_as_float(r << 16);
    return (short)r;
}

// ---- prep: x -> xb (row-major packed bf16); weights -> hi/lo planes ----
__global__ void k_prep(const float* __restrict__ x, uint32* __restrict__ xb,
                       long n4,
                       const float* __restrict__ W1l, const float* __restrict__ W1r,
                       const float* __restrict__ W2l, const float* __restrict__ W2r,
                       short* __restrict__ W1pH, short* __restrict__ W1pL,
                       short* __restrict__ W2pH, short* __restrict__ W2pL) {
    long i = (long)blockIdx.x * blockDim.x + threadIdx.x;
    float back;
    if (i < n4) {
        float4 v = ((const float4*)x)[i];
        short h0 = rne16(v.x, &back);
        short h1 = rne16(v.y, &back);
        short h2 = rne16(v.z, &back);
        short h3 = rne16(v.w, &back);
        uint2 o;
        o.x = (uint32)(unsigned short)h0 | ((uint32)(unsigned short)h1 << 16);
        o.y = (uint32)(unsigned short)h2 | ((uint32)(unsigned short)h3 << 16);
        ((uint2*)xb)[i] = o;
        return;
    }
    int i2 = (int)(i - n4);
    if (i2 < 32768) {
        int j = i2 >> 8, k = i2 & 255;
        float v = (k < 128) ? W1l[j * 128 + k] : W1r[j * 128 + k - 128];
        float hb;
        short hs = rne16(v, &hb);
        short ls = rne16(v - hb, &back);
        int idx = (k >> 3) * 1024 + j * 8 + (k & 7);
        W1pH[idx] = hs;
        W1pL[idx] = ls;
    } else if (i2 < 32768 + 16384) {
        int i3 = i2 - 32768;
        int j = i3 >> 7, k = i3 & 127;
        float v = (j < 64) ? W2l[j * 128 + k] : W2r[(j - 64) * 128 + k];
        float hb;
        short hs = rne16(v, &hb);
        short ls = rne16(v - hb, &back);
        int idx = (k >> 3) * 1024 + j * 8 + (k & 7);
        W2pH[idx] = hs;
        W2pL[idx] = ls;
    }
}

// ---- direct CSR build: deg -> scan -> scatter ----

__global__ void k_deg(const int* __restrict__ ei, int E, int* __restrict__ deg) {
    int stride = gridDim.x * 256;
    for (int e = blockIdx.x * 256 + threadIdx.x; e < E; e += stride)
        atomicAdd(&deg[ei[E + e]], 1);
}

// one block, 1024 threads; chunk = ceil(N/1024) rounded to x4 for int4.
__global__ void k_scan(const int* __restrict__ deg, int* __restrict__ rp,
                       int* __restrict__ cur, int N, int E) {
    __shared__ int part[1024];
    int t = threadIdx.x;
    int chunk = (((N + 1023) >> 10) + 3) & ~3;
    int beg = t * chunk;
    int end = min(beg + chunk, N);
    int s = 0;
    for (int i = beg; i < end; i += 4) {
        if (i + 4 <= end) {
            int4 v = *(const int4*)(deg + i);
            s += v.x + v.y + v.z + v.w;
        } else {
            for (int j = i; j < end; j++) s += deg[j];
        }
    }
    part[t] = s;
    __syncthreads();
    for (int o = 1; o < 1024; o <<= 1) {
        int u = (t >= o) ? part[t - o] : 0;
        __syncthreads();
        part[t] += u;
        __syncthreads();
    }
    int run = part[t] - s;  // exclusive base
    for (int i = beg; i < end; i += 4) {
        if (i + 4 <= end) {
            int4 v = *(const int4*)(deg + i);
            int4 o;
            o.x = run; run += v.x;
            o.y = run; run += v.y;
            o.z = run; run += v.z;
            o.w = run; run += v.w;
            *(int4*)(rp + i) = o;
            *(int4*)(cur + i) = o;
        } else {
            for (int j = i; j < end; j++) {
                rp[j] = run;
                cur[j] = run;
                run += deg[j];
            }
        }
    }
    if (t == 0) rp[N] = E;
}

__global__ void k_scatter(const int* __restrict__ ei, int E,
                          int* __restrict__ cur, int* __restrict__ col) {
    int stride = gridDim.x * 256;
    for (int e = blockIdx.x * 256 + threadIdx.x; e < E; e += stride) {
        int d = ei[E + e];
        int s = ei[e];
        int r = atomicAdd(&cur[d], 1);
        col[r] = s;
    }
}

// ---- fused gather-mean + 2x MFMA GEMM (byte-identical to R19, 99us) ----

__global__ __launch_bounds__(256, 4) void k_fused(
        const int* __restrict__ rp, const int* __restrict__ col,
        const uint32* __restrict__ xb,
        const short* __restrict__ W1pH, const short* __restrict__ W1pL,
        const short* __restrict__ W2pH, const short* __restrict__ W2pL,
        const float* __restrict__ b1, const float* __restrict__ b2,
        unsigned short* __restrict__ hl, float* __restrict__ hr, int N) {
    __shared__ short smH[16 * PSTR];  // mean hi planes; reused for h hi
    __shared__ short smL[16 * PSTR];  // mean lo planes; reused for h lo
    int t = threadIdx.x;
    int w = t >> 6, lane = t & 63;
    int node0 = blockIdx.x * 32;

    // phase A: gather-mean for 8 nodes/wave. rp prefetched via one load.
    int base = node0 + 8 * w;
    int rpi = base + lane;
    if (rpi > N) rpi = N;
    int rpv = rp[rpi];

#define ACC1(a) { s += (f32x2){bf_lo(a), __uint_as_float(a)}; }

    for (int i = 0; i < 8; i++) {
        int lr = 8 * w + i;
        int beg = __builtin_amdgcn_readfirstlane(__shfl(rpv, i));
        int end = __builtin_amdgcn_readfirstlane(__shfl(rpv, i + 1));
        f32x2 s = (f32x2){0.f, 0.f};
        int e = beg;
        for (; e + 8 <= end; e += 8) {
            int c0 = col[e + 0], c1 = col[e + 1], c2 = col[e + 2], c3 = col[e + 3];
            int c4 = col[e + 4], c5 = col[e + 5], c6 = col[e + 6], c7 = col[e + 7];
            uint32 a0 = xb[(size_t)c0 * 64 + lane];
            uint32 a1 = xb[(size_t)c1 * 64 + lane];
            uint32 a2 = xb[(size_t)c2 * 64 + lane];
            uint32 a3 = xb[(size_t)c3 * 64 + lane];
            uint32 a4 = xb[(size_t)c4 * 64 + lane];
            uint32 a5 = xb[(size_t)c5 * 64 + lane];
            uint32 a6 = xb[(size_t)c6 * 64 + lane];
            uint32 a7 = xb[(size_t)c7 * 64 + lane];
            ACC1(a0); ACC1(a1); ACC1(a2); ACC1(a3);
            ACC1(a4); ACC1(a5); ACC1(a6); ACC1(a7);
        }
        for (; e + 4 <= end; e += 4) {
            int c0 = col[e + 0], c1 = col[e + 1], c2 = col[e + 2], c3 = col[e + 3];
            uint32 a0 = xb[(size_t)c0 * 64 + lane];
            uint32 a1 = xb[(size_t)c1 * 64 + lane];
            uint32 a2 = xb[(size_t)c2 * 64 + lane];
            uint32 a3 = xb[(size_t)c3 * 64 + lane];
            ACC1(a0); ACC1(a1); ACC1(a2); ACC1(a3);
        }
        for (; e < end; e++) {
            uint32 a0 = xb[(size_t)col[e] * 64 + lane];
            ACC1(a0);
        }
        // epilogue: lane l -> plane l>>2, node lr, shorts 2(l&3)..+1
        float inv = 1.0f / (float)max(end - beg, 1);
        float m0 = s.x * inv, m1 = s.y * inv;
        float b_;
        short h0 = rne16(m0, &b_);
        float bk0 = b_;
        short l0 = rne16(m0 - bk0, &b_);
        short h1 = rne16(m1, &b_);
        float bk1 = b_;
        short l1 = rne16(m1 - bk1, &b_);
        uint32 H = (uint32)(unsigned short)h0 | ((uint32)(unsigned short)h1 << 16);
        uint32 L = (uint32)(unsigned short)l0 | ((uint32)(unsigned short)l1 << 16);
        int idx = (lane >> 2) * PSTR + lr * 8 + 2 * (lane & 3);
        *(uint32*)&smH[idx] = H;
        *(uint32*)&smL[idx] = L;
    }
#undef ACC1
    __syncthreads();

    // phase B: GEMM1 (mean hi/lo from LDS + x hi direct from xb), tile jt=w
    int m = lane & 31, hh = lane >> 5;
    int mynode = node0 + m;
    const short* xbs = (const short*)xb;  // row = 128 shorts (feature order)
    f32x16 acc;
#pragma unroll
    for (int r = 0; r < 16; r++) acc[r] = 0.f;
#pragma unroll
    for (int kc = 0; kc < 8; kc++) {
        int c = 2 * kc + hh;
        bf16x8 bH = *(const bf16x8*)&smH[c * PSTR + m * 8];
        bf16x8 bL = *(const bf16x8*)&smL[c * PSTR + m * 8];
        bf16x8 xH = *(const bf16x8*)(xbs + (size_t)mynode * 128 + c * 8);
        bf16x8 aH1 = *(const bf16x8*)(W1pH + c * 1024 + (32 * w + m) * 8);
        bf16x8 aL1 = *(const bf16x8*)(W1pL + c * 1024 + (32 * w + m) * 8);
        bf16x8 aH2 = *(const bf16x8*)(W1pH + (16 + c) * 1024 + (32 * w + m) * 8);
        bf16x8 aL2 = *(const bf16x8*)(W1pL + (16 + c) * 1024 + (32 * w + m) * 8);
        acc = __builtin_amdgcn_mfma_f32_32x32x16_bf16(aH1, bH, acc, 0, 0, 0);
        acc = __builtin_amdgcn_mfma_f32_32x32x16_bf16(aL1, bH, acc, 0, 0, 0);
        acc = __builtin_amdgcn_mfma_f32_32x32x16_bf16(aH1, bL, acc, 0, 0, 0);
        acc = __builtin_amdgcn_mfma_f32_32x32x16_bf16(aH2, xH, acc, 0, 0, 0);
        acc = __builtin_amdgcn_mfma_f32_32x32x16_bf16(aL2, xH, acc, 0, 0, 0);
    }

    // epilogue 1: relu + b1 -> h (hi/lo) in regs
    uint2 oh[4], ol[4];
#pragma unroll
    for (int rg = 0; rg < 4; rg++) {
        int j0 = 32 * w + 8 * rg + 4 * hh;
        float4 bv = *(const float4*)(b1 + j0);
        float bb[4] = {bv.x, bv.y, bv.z, bv.w};
        short hs[4], ls[4];
#pragma unroll
        for (int q = 0; q < 4; q++) {
            float v = fmaxf(acc[4 * rg + q] + bb[q], 0.f);
            float back;
            hs[q] = rne16(v, &back);
            ls[q] = rne16(v - back, &back);
        }
        oh[rg].x = (uint32)(unsigned short)hs[0] | ((uint32)(unsigned short)hs[1] << 16);
        oh[rg].y = (uint32)(unsigned short)hs[2] | ((uint32)(unsigned short)hs[3] << 16);
        ol[rg].x = (uint32)(unsigned short)ls[0] | ((uint32)(unsigned short)ls[1] << 16);
        ol[rg].y = (uint32)(unsigned short)ls[2] | ((uint32)(unsigned short)ls[3] << 16);
    }
    __syncthreads();  // all waves done reading mean planes
#pragma unroll
    for (int rg = 0; rg < 4; rg++) {
        int idx = (4 * w + rg) * PSTR + m * 8 + 4 * hh;  // plane j>>3 = 4w+rg
        *(uint2*)&smH[idx] = oh[rg];
        *(uint2*)&smL[idx] = ol[rg];
    }
    __syncthreads();

    // GEMM2: B-fragments from LDS h planes, tile jt=w
#pragma unroll
    for (int r = 0; r < 16; r++) acc[r] = 0.f;
#pragma unroll
    for (int kc = 0; kc < 8; kc++) {
        int c = 2 * kc + hh;
        bf16x8 bH = *(const bf16x8*)&smH[c * PSTR + m * 8];
        bf16x8 bL = *(const bf16x8*)&smL[c * PSTR + m * 8];
        bf16x8 aH = *(const bf16x8*)(W2pH + c * 1024 + (32 * w + m) * 8);
        bf16x8 aL = *(const bf16x8*)(W2pL + c * 1024 + (32 * w + m) * 8);
        acc = __builtin_amdgcn_mfma_f32_32x32x16_bf16(aH, bH, acc, 0, 0, 0);
        acc = __builtin_amdgcn_mfma_f32_32x32x16_bf16(aL, bH, acc, 0, 0, 0);
        acc = __builtin_amdgcn_mfma_f32_32x32x16_bf16(aH, bL, acc, 0, 0, 0);
    }
    if (mynode >= N) return;
    if (w < 2) {
        // waves 0,1: cols 0..63 = h @ W2l^T -> hl (bf16)
#pragma unroll
        for (int rg = 0; rg < 4; rg++) {
            int j0 = 32 * w + 8 * rg + 4 * hh;
            uint2 o;
            o.x = pack_bf16_rne(acc[4 * rg + 0], acc[4 * rg + 1]);
            o.y = pack_bf16_rne(acc[4 * rg + 2], acc[4 * rg + 3]);
            *(uint2*)&hl[(size_t)mynode * 64 + j0] = o;
        }
    } else {
        // waves 2,3: cols 64..127 = h @ W2r^T + b2 -> hr (fp32)
#pragma unroll
        for (int rg = 0; rg < 4; rg++) {
            int j0 = 32 * (w - 2) + 8 * rg + 4 * hh;
            float4 bv = *(const float4*)(b2 + j0);
            float4 o;
            o.x = acc[4 * rg + 0] + bv.x;
            o.y = acc[4 * rg + 1] + bv.y;
            o.z = acc[4 * rg + 2] + bv.z;
            o.w = acc[4 * rg + 3] + bv.w;
            *(float4*)&hr[(size_t)mynode * 64 + j0] = o;
        }
    }
}

// ---- aggregation 2 (byte-identical to R19) ----

__global__ void k_agg_out(const int* __restrict__ rp, const int* __restrict__ col,
                          const unsigned short* __restrict__ hl,
                          const float* __restrict__ hr,
                          float* __restrict__ out, int N) {
    int node = blockIdx.x * 8 + (threadIdx.x >> 5);  // half-wave per node
    if (node >= N) return;
    int h = threadIdx.x & 31;
    int g = h >> 3;   // 4 groups
    int f = h & 7;    // 8 lanes: features [8f, 8f+8)
    int beg = rp[node], end = rp[node + 1];
    const uint4* hl4 = (const uint4*)hl;  // row = 8 uint4 (128B)
    f32x2 sA[4];
#pragma unroll
    for (int j = 0; j < 4; j++) sA[j] = (f32x2){0.f, 0.f};

#define ACC_MSK(v)                                          \
    { sA[0] += (f32x2){bf_lo(v.x), bf_hi(v.x)};             \
      sA[1] += (f32x2){bf_lo(v.y), bf_hi(v.y)};             \
      sA[2] += (f32x2){bf_lo(v.z), bf_hi(v.z)};             \
      sA[3] += (f32x2){bf_lo(v.w), bf_hi(v.w)}; }

    int e = beg;
    for (; e + 16 <= end; e += 16) {
        uint4 cv = *(const uint4*)(col + e + 4 * g);
        uint4 v0 = hl4[(size_t)cv.x * 8 + f];
        uint4 v1 = hl4[(size_t)cv.y * 8 + f];
        uint4 v2 = hl4[(size_t)cv.z * 8 + f];
        uint4 v3 = hl4[(size_t)cv.w * 8 + f];
        ACC_MSK(v0); ACC_MSK(v1); ACC_MSK(v2); ACC_MSK(v3);
    }
    for (; e + 8 <= end; e += 8) {
        uint2 cv = *(const uint2*)(col + e + 2 * g);
        uint4 v0 = hl4[(size_t)cv.x * 8 + f];
        uint4 v1 = hl4[(size_t)cv.y * 8 + f];
        ACC_MSK(v0); ACC_MSK(v1);
    }
    int rem = end - e;
    if (2 * g < rem) {
        uint4 v0 = hl4[(size_t)col[e + 2 * g] * 8 + f];
        ACC_MSK(v0);
    }
    if (2 * g + 1 < rem) {
        uint4 v0 = hl4[(size_t)col[e + 2 * g + 1] * 8 + f];
        ACC_MSK(v0);
    }
#undef ACC_MSK
    // reduce over the 4 groups (stays within the 32-lane half)
#pragma unroll
    for (int p = 0; p < 4; p++) {
        sA[p].x += __shfl_xor(sA[p].x, 8);
        sA[p].y += __shfl_xor(sA[p].y, 8);
        sA[p].x += __shfl_xor(sA[p].x, 16);
        sA[p].y += __shfl_xor(sA[p].y, 16);
    }
    if (g == 0) {
        float inv = 1.0f / (float)max(end - beg, 1);
        const float* hrp = hr + (size_t)node * 64 + f * 8;
        float4 h0 = *(const float4*)(hrp);
        float4 h1 = *(const float4*)(hrp + 4);
        float4 o0, o1;
        o0.x = sA[0].x * inv + h0.x;
        o0.y = sA[0].y * inv + h0.y;
        o0.z = sA[1].x * inv + h0.z;
        o0.w = sA[1].y * inv + h0.w;
        o1.x = sA[2].x * inv + h1.x;
        o1.y = sA[2].y * inv + h1.y;
        o1.z = sA[3].x * inv + h1.z;
        o1.w = sA[3].y * inv + h1.w;
        float* op = out + (size_t)node * 64 + f * 8;
        *(float4*)(op) = o0;
        *(float4*)(op + 4) = o1;
    }
}

extern "C" void kernel_launch(void* const* d_in, const int* in_sizes, int n_in,
                              void* d_out, int out_size, void* d_ws, size_t ws_size,
                              hipStream_t stream) {
    const float* x   = (const float*)d_in[0];
    const float* W1l = (const float*)d_in[1];
    const float* W1r = (const float*)d_in[2];
    const float* b1  = (const float*)d_in[3];
    const float* W2l = (const float*)d_in[4];
    const float* W2r = (const float*)d_in[5];
    const float* b2  = (const float*)d_in[6];
    const int*   ei  = (const int*)d_in[7];
    int N = in_sizes[0] / 128;
    int E = in_sizes[7] / 2;
    int mb = (N + 31) / 32;
    int Np = ((N + 127) / 128) * 128;  // padded node count
    float* out = (float*)d_out;

    char* w = (char*)d_ws;
    size_t off = 0;
    auto alloc = [&](size_t bytes) -> char* {
        char* p = w + off;
        off += (bytes + 255) & ~(size_t)255;
        return p;
    };
    int*   row_ptr = (int*)alloc((size_t)(N + 1) * 4);
    int*   deg     = (int*)alloc((size_t)(N + 1) * 4);
    int*   cur     = (int*)alloc((size_t)(N + 1) * 4);
    short* W1pH    = (short*)alloc(32768 * 2);
    short* W1pL    = (short*)alloc(32768 * 2);
    short* W2pH    = (short*)alloc(16384 * 2);
    short* W2pL    = (short*)alloc(16384 * 2);
    int*   col     = (int*)alloc((size_t)E * 4);
    uint32* xb     = (uint32*)alloc((size_t)Np * 64 * 4);   // 25.6 MB
    float*  hr     = (float*)alloc((size_t)Np * 64 * 4);    // 25.6 MB
    unsigned short* hl = (unsigned short*)alloc((size_t)N * 64 * 2);  // 12.8 MB

    hipMemsetAsync(deg, 0, (size_t)N * 4, stream);
    long n4 = (long)N * 32;
    long prep_items = n4 + 32768 + 16384;
    k_prep<<<(int)((prep_items + 255) / 256), 256, 0, stream>>>(
        x, xb, n4, W1l, W1r, W2l, W2r, W1pH, W1pL, W2pH, W2pL);
    k_deg<<<2048, 256, 0, stream>>>(ei, E, deg);
    k_scan<<<1, 1024, 0, stream>>>(deg, row_ptr, cur, N, E);
    k_scatter<<<2048, 256, 0, stream>>>(ei, E, cur, col);

    k_fused<<<mb, 256, 0, stream>>>(row_ptr, col, xb, W1pH, W1pL, W2pH, W2pL,
                                    b1, b2, hl, hr, N);
    int ab = (N + 7) / 8;
    k_agg_out<<<ab, 256, 0, stream>>>(row_ptr, col, hl, hr, out, N);
}

// Round 12
// 315.217 us; speedup vs baseline: 1.5682x; 1.5682x over previous
//
#include <hip/hip_runtime.h>

// SAGE_Net: 2-layer GraphSAGE, N=100k, E=1.6M, 128->128->64, fp32.
// R21: R20's direct CSR reverted (k_scatter 149us: random 4B col writes ->
// 16x write amplification, WRITE_SIZE 106MB; bucketing IS the fix). Build
// restored to R19/R14 bucketed form (best: 314.8us total). One new change:
// k_fused phase A prefetches the next iteration's 8 col scalars (SGPRs,
// occupancy-neutral -- R15's VGPR-prefetch lesson applied correctly) so the
// s_load latency overlaps the row-load wait instead of serializing with it.
// Same loads, same ACC order -> bit-identical numerics.

typedef unsigned int uint32;
typedef short bf16x8 __attribute__((ext_vector_type(8)));
typedef float f32x16 __attribute__((ext_vector_type(16)));
typedef float f32x2 __attribute__((ext_vector_type(2)));

#define PSTR 264  // LDS plane stride in shorts (32*8 + 8 pad; 528B)

__device__ __forceinline__ uint32 pack_bf16_rne(float a, float b) {
    uint32 ua = __float_as_uint(a);
    uint32 ub = __float_as_uint(b);
    uint32 ra = (ua + 0x7fffu + ((ua >> 16) & 1u)) >> 16;
    uint32 rb = (ub + 0x7fffu + ((ub >> 16) & 1u)) >> 16;
    return ra | (rb << 16);
}
__device__ __forceinline__ float bf_lo(uint32 v) { return __uint_as_float(v << 16); }
__device__ __forceinline__ float bf_hi(uint32 v) { return __uint_as_float(v & 0xffff0000u); }

__device__ __forceinline__ short rne16(float v, float* back) {
    uint32 u = __float_as_uint(v);
    uint32 r = (u + 0x7fffu + ((u >> 16) & 1u)) >> 16;
    *back = __uint_as_float(r << 16);
    return (short)r;
}

// ---- prep: x -> xb (row-major packed bf16); weights -> hi/lo planes ----
__global__ void k_prep(const float* __restrict__ x, uint32* __restrict__ xb,
                       long n4,
                       const float* __restrict__ W1l, const float* __restrict__ W1r,
                       const float* __restrict__ W2l, const float* __restrict__ W2r,
                       short* __restrict__ W1pH, short* __restrict__ W1pL,
                       short* __restrict__ W2pH, short* __restrict__ W2pL) {
    long i = (long)blockIdx.x * blockDim.x + threadIdx.x;
    float back;
    if (i < n4) {
        float4 v = ((const float4*)x)[i];
        short h0 = rne16(v.x, &back);
        short h1 = rne16(v.y, &back);
        short h2 = rne16(v.z, &back);
        short h3 = rne16(v.w, &back);
        uint2 o;
        o.x = (uint32)(unsigned short)h0 | ((uint32)(unsigned short)h1 << 16);
        o.y = (uint32)(unsigned short)h2 | ((uint32)(unsigned short)h3 << 16);
        ((uint2*)xb)[i] = o;
        return;
    }
    int i2 = (int)(i - n4);
    if (i2 < 32768) {
        int j = i2 >> 8, k = i2 & 255;
        float v = (k < 128) ? W1l[j * 128 + k] : W1r[j * 128 + k - 128];
        float hb;
        short hs = rne16(v, &hb);
        short ls = rne16(v - hb, &back);
        int idx = (k >> 3) * 1024 + j * 8 + (k & 7);
        W1pH[idx] = hs;
        W1pL[idx] = ls;
    } else if (i2 < 32768 + 16384) {
        int i3 = i2 - 32768;
        int j = i3 >> 7, k = i3 & 127;
        float v = (j < 64) ? W2l[j * 128 + k] : W2r[(j - 64) * 128 + k];
        float hb;
        short hs = rne16(v, &hb);
        short ls = rne16(v - hb, &back);
        int idx = (k >> 3) * 1024 + j * 8 + (k & 7);
        W2pH[idx] = hs;
        W2pL[idx] = ls;
    }
}

// ---- bucketed CSR build (R14/R19 form -- best measured) ----

__global__ void k_bcount(const int* __restrict__ ei, int E, int NB,
                         int* __restrict__ bucket_cnt) {
    __shared__ int hist[1024];
    int t = threadIdx.x;
    for (int i = t; i < NB; i += 256) hist[i] = 0;
    __syncthreads();
    int stride = gridDim.x * 256;
    for (int e = blockIdx.x * 256 + t; e < E; e += stride)
        atomicAdd(&hist[ei[E + e] >> 8], 1);
    __syncthreads();
    for (int i = t; i < NB; i += 256) {
        int c = hist[i];
        if (c) atomicAdd(&bucket_cnt[i], c);
    }
}

__global__ void k_bscan(const int* __restrict__ bucket_cnt, int NB, int E,
                        int* __restrict__ bucket_off, int* __restrict__ bucket_cur) {
    __shared__ int s[1024];
    int t = threadIdx.x;
    int v = (t < NB) ? bucket_cnt[t] : 0;
    s[t] = v;
    __syncthreads();
    for (int o = 1; o < 1024; o <<= 1) {
        int u = (t >= o) ? s[t - o] : 0;
        __syncthreads();
        s[t] += u;
        __syncthreads();
    }
    int ex = s[t] - v;
    if (t < NB) { bucket_off[t] = ex; bucket_cur[t] = ex; }
    if (t == NB - 1) bucket_off[NB] = ex + v;
}

__global__ void k_bscatter(const int* __restrict__ ei, int E, int NB,
                           int* __restrict__ bucket_cur, uint32* __restrict__ eb) {
    __shared__ int hist[1024];
    __shared__ int base[1024];
    int t = threadIdx.x;
    for (int i = t; i < NB; i += 256) hist[i] = 0;
    __syncthreads();
    int stride = gridDim.x * 256;
    for (int e = blockIdx.x * 256 + t; e < E; e += stride)
        atomicAdd(&hist[ei[E + e] >> 8], 1);
    __syncthreads();
    for (int i = t; i < NB; i += 256) {
        int c = hist[i];
        base[i] = c ? atomicAdd(&bucket_cur[i], c) : 0;
        hist[i] = 0;
    }
    __syncthreads();
    for (int e = blockIdx.x * 256 + t; e < E; e += stride) {
        int d = ei[E + e];
        int b = d >> 8;
        int r = atomicAdd(&hist[b], 1);
        eb[base[b] + r] = ((uint32)(d & 255) << 24) | (uint32)ei[e];
    }
}

__global__ void k_bfinal(const uint32* __restrict__ eb,
                         const int* __restrict__ bucket_off,
                         int* __restrict__ row_ptr, int* __restrict__ col,
                         int N, int E) {
    __shared__ int deg[256];
    __shared__ int sc[256];
    __shared__ int cur[256];
    int b = blockIdx.x;
    int t = threadIdx.x;
    int beg = bucket_off[b], end = bucket_off[b + 1];
    deg[t] = 0;
    __syncthreads();
    for (int e = beg + t; e < end; e += 256)
        atomicAdd(&deg[eb[e] >> 24], 1);
    __syncthreads();
    int v = deg[t];
    sc[t] = v;
    __syncthreads();
    for (int o = 1; o < 256; o <<= 1) {
        int u = (t >= o) ? sc[t - o] : 0;
        __syncthreads();
        sc[t] += u;
        __syncthreads();
    }
    int ex = sc[t] - v;
    int node = b * 256 + t;
    if (node < N) row_ptr[node] = beg + ex;
    if (b == gridDim.x - 1 && t == 0) row_ptr[N] = E;
    cur[t] = ex;
    __syncthreads();
    for (int e = beg + t; e < end; e += 256) {
        uint32 u = eb[e];
        int r = atomicAdd(&cur[u >> 24], 1);
        col[beg + r] = (int)(u & 0xFFFFFFu);
    }
}

// ---- fused gather-mean + 2x MFMA GEMM. Block = 32 nodes, 4 waves.
// R21: phase A 8-edge loop software-pipelines the wave-uniform col scalars
// (SGPR-only prefetch; row loads and ACC order unchanged -> bit-identical).

__global__ __launch_bounds__(256, 4) void k_fused(
        const int* __restrict__ rp, const int* __restrict__ col,
        const uint32* __restrict__ xb,
        const short* __restrict__ W1pH, const short* __restrict__ W1pL,
        const short* __restrict__ W2pH, const short* __restrict__ W2pL,
        const float* __restrict__ b1, const float* __restrict__ b2,
        unsigned short* __restrict__ hl, float* __restrict__ hr, int N) {
    __shared__ short smH[16 * PSTR];  // mean hi planes; reused for h hi
    __shared__ short smL[16 * PSTR];  // mean lo planes; reused for h lo
    int t = threadIdx.x;
    int w = t >> 6, lane = t & 63;
    int node0 = blockIdx.x * 32;

    // phase A: gather-mean for 8 nodes/wave. rp prefetched via one load.
    int base = node0 + 8 * w;
    int rpi = base + lane;
    if (rpi > N) rpi = N;
    int rpv = rp[rpi];

#define ACC1(a) { s += (f32x2){bf_lo(a), __uint_as_float(a)}; }

    for (int i = 0; i < 8; i++) {
        int lr = 8 * w + i;
        int beg = __builtin_amdgcn_readfirstlane(__shfl(rpv, i));
        int end = __builtin_amdgcn_readfirstlane(__shfl(rpv, i + 1));
        f32x2 s = (f32x2){0.f, 0.f};
        int e = beg;
        // SGPR col software pipeline: prefetch next 8 while rows load.
        int p0, p1, p2, p3, p4, p5, p6, p7;
        bool have = (e + 8 <= end);
        if (have) {
            p0 = col[e + 0]; p1 = col[e + 1]; p2 = col[e + 2]; p3 = col[e + 3];
            p4 = col[e + 4]; p5 = col[e + 5]; p6 = col[e + 6]; p7 = col[e + 7];
        }
        while (have) {
            int c0 = p0, c1 = p1, c2 = p2, c3 = p3;
            int c4 = p4, c5 = p5, c6 = p6, c7 = p7;
            int en = e + 8;
            bool hn = (en + 8 <= end);
            if (hn) {
                p0 = col[en + 0]; p1 = col[en + 1]; p2 = col[en + 2]; p3 = col[en + 3];
                p4 = col[en + 4]; p5 = col[en + 5]; p6 = col[en + 6]; p7 = col[en + 7];
            }
            uint32 a0 = xb[(size_t)c0 * 64 + lane];
            uint32 a1 = xb[(size_t)c1 * 64 + lane];
            uint32 a2 = xb[(size_t)c2 * 64 + lane];
            uint32 a3 = xb[(size_t)c3 * 64 + lane];
            uint32 a4 = xb[(size_t)c4 * 64 + lane];
            uint32 a5 = xb[(size_t)c5 * 64 + lane];
            uint32 a6 = xb[(size_t)c6 * 64 + lane];
            uint32 a7 = xb[(size_t)c7 * 64 + lane];
            ACC1(a0); ACC1(a1); ACC1(a2); ACC1(a3);
            ACC1(a4); ACC1(a5); ACC1(a6); ACC1(a7);
            e = en;
            have = hn;
        }
        for (; e + 4 <= end; e += 4) {
            int c0 = col[e + 0], c1 = col[e + 1], c2 = col[e + 2], c3 = col[e + 3];
            uint32 a0 = xb[(size_t)c0 * 64 + lane];
            uint32 a1 = xb[(size_t)c1 * 64 + lane];
            uint32 a2 = xb[(size_t)c2 * 64 + lane];
            uint32 a3 = xb[(size_t)c3 * 64 + lane];
            ACC1(a0); ACC1(a1); ACC1(a2); ACC1(a3);
        }
        for (; e < end; e++) {
            uint32 a0 = xb[(size_t)col[e] * 64 + lane];
            ACC1(a0);
        }
        // epilogue: lane l -> plane l>>2, node lr, shorts 2(l&3)..+1
        float inv = 1.0f / (float)max(end - beg, 1);
        float m0 = s.x * inv, m1 = s.y * inv;
        float b_;
        short h0 = rne16(m0, &b_);
        float bk0 = b_;
        short l0 = rne16(m0 - bk0, &b_);
        short h1 = rne16(m1, &b_);
        float bk1 = b_;
        short l1 = rne16(m1 - bk1, &b_);
        uint32 H = (uint32)(unsigned short)h0 | ((uint32)(unsigned short)h1 << 16);
        uint32 L = (uint32)(unsigned short)l0 | ((uint32)(unsigned short)l1 << 16);
        int idx = (lane >> 2) * PSTR + lr * 8 + 2 * (lane & 3);
        *(uint32*)&smH[idx] = H;
        *(uint32*)&smL[idx] = L;
    }
#undef ACC1
    __syncthreads();

    // phase B: GEMM1 (mean hi/lo from LDS + x hi direct from xb), tile jt=w
    int m = lane & 31, hh = lane >> 5;
    int mynode = node0 + m;
    const short* xbs = (const short*)xb;  // row = 128 shorts (feature order)
    f32x16 acc;
#pragma unroll
    for (int r = 0; r < 16; r++) acc[r] = 0.f;
#pragma unroll
    for (int kc = 0; kc < 8; kc++) {
        int c = 2 * kc + hh;
        bf16x8 bH = *(const bf16x8*)&smH[c * PSTR + m * 8];
        bf16x8 bL = *(const bf16x8*)&smL[c * PSTR + m * 8];
        bf16x8 xH = *(const bf16x8*)(xbs + (size_t)mynode * 128 + c * 8);
        bf16x8 aH1 = *(const bf16x8*)(W1pH + c * 1024 + (32 * w + m) * 8);
        bf16x8 aL1 = *(const bf16x8*)(W1pL + c * 1024 + (32 * w + m) * 8);
        bf16x8 aH2 = *(const bf16x8*)(W1pH + (16 + c) * 1024 + (32 * w + m) * 8);
        bf16x8 aL2 = *(const bf16x8*)(W1pL + (16 + c) * 1024 + (32 * w + m) * 8);
        acc = __builtin_amdgcn_mfma_f32_32x32x16_bf16(aH1, bH, acc, 0, 0, 0);
        acc = __builtin_amdgcn_mfma_f32_32x32x16_bf16(aL1, bH, acc, 0, 0, 0);
        acc = __builtin_amdgcn_mfma_f32_32x32x16_bf16(aH1, bL, acc, 0, 0, 0);
        acc = __builtin_amdgcn_mfma_f32_32x32x16_bf16(aH2, xH, acc, 0, 0, 0);
        acc = __builtin_amdgcn_mfma_f32_32x32x16_bf16(aL2, xH, acc, 0, 0, 0);
    }

    // epilogue 1: relu + b1 -> h (hi/lo) in regs
    uint2 oh[4], ol[4];
#pragma unroll
    for (int rg = 0; rg < 4; rg++) {
        int j0 = 32 * w + 8 * rg + 4 * hh;
        float4 bv = *(const float4*)(b1 + j0);
        float bb[4] = {bv.x, bv.y, bv.z, bv.w};
        short hs[4], ls[4];
#pragma unroll
        for (int q = 0; q < 4; q++) {
            float v = fmaxf(acc[4 * rg + q] + bb[q], 0.f);
            float back;
            hs[q] = rne16(v, &back);
            ls[q] = rne16(v - back, &back);
        }
        oh[rg].x = (uint32)(unsigned short)hs[0] | ((uint32)(unsigned short)hs[1] << 16);
        oh[rg].y = (uint32)(unsigned short)hs[2] | ((uint32)(unsigned short)hs[3] << 16);
        ol[rg].x = (uint32)(unsigned short)ls[0] | ((uint32)(unsigned short)ls[1] << 16);
        ol[rg].y = (uint32)(unsigned short)ls[2] | ((uint32)(unsigned short)ls[3] << 16);
    }
    __syncthreads();  // all waves done reading mean planes
#pragma unroll
    for (int rg = 0; rg < 4; rg++) {
        int idx = (4 * w + rg) * PSTR + m * 8 + 4 * hh;  // plane j>>3 = 4w+rg
        *(uint2*)&smH[idx] = oh[rg];
        *(uint2*)&smL[idx] = ol[rg];
    }
    __syncthreads();

    // GEMM2: B-fragments from LDS h planes, tile jt=w
#pragma unroll
    for (int r = 0; r < 16; r++) acc[r] = 0.f;
#pragma unroll
    for (int kc = 0; kc < 8; kc++) {
        int c = 2 * kc + hh;
        bf16x8 bH = *(const bf16x8*)&smH[c * PSTR + m * 8];
        bf16x8 bL = *(const bf16x8*)&smL[c * PSTR + m * 8];
        bf16x8 aH = *(const bf16x8*)(W2pH + c * 1024 + (32 * w + m) * 8);
        bf16x8 aL = *(const bf16x8*)(W2pL + c * 1024 + (32 * w + m) * 8);
        acc = __builtin_amdgcn_mfma_f32_32x32x16_bf16(aH, bH, acc, 0, 0, 0);
        acc = __builtin_amdgcn_mfma_f32_32x32x16_bf16(aL, bH, acc, 0, 0, 0);
        acc = __builtin_amdgcn_mfma_f32_32x32x16_bf16(aH, bL, acc, 0, 0, 0);
    }
    if (mynode >= N) return;
    if (w < 2) {
        // waves 0,1: cols 0..63 = h @ W2l^T -> hl (bf16)
#pragma unroll
        for (int rg = 0; rg < 4; rg++) {
            int j0 = 32 * w + 8 * rg + 4 * hh;
            uint2 o;
            o.x = pack_bf16_rne(acc[4 * rg + 0], acc[4 * rg + 1]);
            o.y = pack_bf16_rne(acc[4 * rg + 2], acc[4 * rg + 3]);
            *(uint2*)&hl[(size_t)mynode * 64 + j0] = o;
        }
    } else {
        // waves 2,3: cols 64..127 = h @ W2r^T + b2 -> hr (fp32)
#pragma unroll
        for (int rg = 0; rg < 4; rg++) {
            int j0 = 32 * (w - 2) + 8 * rg + 4 * hh;
            float4 bv = *(const float4*)(b2 + j0);
            float4 o;
            o.x = acc[4 * rg + 0] + bv.x;
            o.y = acc[4 * rg + 1] + bv.y;
            o.z = acc[4 * rg + 2] + bv.z;
            o.w = acc[4 * rg + 3] + bv.w;
            *(float4*)&hr[(size_t)mynode * 64 + j0] = o;
        }
    }
}

// ---- aggregation 2 (byte-identical to R19) ----

__global__ void k_agg_out(const int* __restrict__ rp, const int* __restrict__ col,
                          const unsigned short* __restrict__ hl,
                          const float* __restrict__ hr,
                          float* __restrict__ out, int N) {
    int node = blockIdx.x * 8 + (threadIdx.x >> 5);  // half-wave per node
    if (node >= N) return;
    int h = threadIdx.x & 31;
    int g = h >> 3;   // 4 groups
    int f = h & 7;    // 8 lanes: features [8f, 8f+8)
    int beg = rp[node], end = rp[node + 1];
    const uint4* hl4 = (const uint4*)hl;  // row = 8 uint4 (128B)
    f32x2 sA[4];
#pragma unroll
    for (int j = 0; j < 4; j++) sA[j] = (f32x2){0.f, 0.f};

#define ACC_MSK(v)                                          \
    { sA[0] += (f32x2){bf_lo(v.x), bf_hi(v.x)};             \
      sA[1] += (f32x2){bf_lo(v.y), bf_hi(v.y)};             \
      sA[2] += (f32x2){bf_lo(v.z), bf_hi(v.z)};             \
      sA[3] += (f32x2){bf_lo(v.w), bf_hi(v.w)}; }

    int e = beg;
    for (; e + 16 <= end; e += 16) {
        uint4 cv = *(const uint4*)(col + e + 4 * g);
        uint4 v0 = hl4[(size_t)cv.x * 8 + f];
        uint4 v1 = hl4[(size_t)cv.y * 8 + f];
        uint4 v2 = hl4[(size_t)cv.z * 8 + f];
        uint4 v3 = hl4[(size_t)cv.w * 8 + f];
        ACC_MSK(v0); ACC_MSK(v1); ACC_MSK(v2); ACC_MSK(v3);
    }
    for (; e + 8 <= end; e += 8) {
        uint2 cv = *(const uint2*)(col + e + 2 * g);
        uint4 v0 = hl4[(size_t)cv.x * 8 + f];
        uint4 v1 = hl4[(size_t)cv.y * 8 + f];
        ACC_MSK(v0); ACC_MSK(v1);
    }
    int rem = end - e;
    if (2 * g < rem) {
        uint4 v0 = hl4[(size_t)col[e + 2 * g] * 8 + f];
        ACC_MSK(v0);
    }
    if (2 * g + 1 < rem) {
        uint4 v0 = hl4[(size_t)col[e + 2 * g + 1] * 8 + f];
        ACC_MSK(v0);
    }
#undef ACC_MSK
    // reduce over the 4 groups (stays within the 32-lane half)
#pragma unroll
    for (int p = 0; p < 4; p++) {
        sA[p].x += __shfl_xor(sA[p].x, 8);
        sA[p].y += __shfl_xor(sA[p].y, 8);
        sA[p].x += __shfl_xor(sA[p].x, 16);
        sA[p].y += __shfl_xor(sA[p].y, 16);
    }
    if (g == 0) {
        float inv = 1.0f / (float)max(end - beg, 1);
        const float* hrp = hr + (size_t)node * 64 + f * 8;
        float4 h0 = *(const float4*)(hrp);
        float4 h1 = *(const float4*)(hrp + 4);
        float4 o0, o1;
        o0.x = sA[0].x * inv + h0.x;
        o0.y = sA[0].y * inv + h0.y;
        o0.z = sA[1].x * inv + h0.z;
        o0.w = sA[1].y * inv + h0.w;
        o1.x = sA[2].x * inv + h1.x;
        o1.y = sA[2].y * inv + h1.y;
        o1.z = sA[3].x * inv + h1.z;
        o1.w = sA[3].y * inv + h1.w;
        float* op = out + (size_t)node * 64 + f * 8;
        *(float4*)(op) = o0;
        *(float4*)(op + 4) = o1;
    }
}

extern "C" void kernel_launch(void* const* d_in, const int* in_sizes, int n_in,
                              void* d_out, int out_size, void* d_ws, size_t ws_size,
                              hipStream_t stream) {
    const float* x   = (const float*)d_in[0];
    const float* W1l = (const float*)d_in[1];
    const float* W1r = (const float*)d_in[2];
    const float* b1  = (const float*)d_in[3];
    const float* W2l = (const float*)d_in[4];
    const float* W2r = (const float*)d_in[5];
    const float* b2  = (const float*)d_in[6];
    const int*   ei  = (const int*)d_in[7];
    int N = in_sizes[0] / 128;
    int E = in_sizes[7] / 2;
    int NB = (N + 255) >> 8;
    int mb = (N + 31) / 32;
    int Np = ((N + 127) / 128) * 128;  // padded node count
    float* out = (float*)d_out;

    char* w = (char*)d_ws;
    size_t off = 0;
    auto alloc = [&](size_t bytes) -> char* {
        char* p = w + off;
        off += (bytes + 255) & ~(size_t)255;
        return p;
    };
    int*   row_ptr = (int*)alloc((size_t)(N + 1) * 4);
    int*   bcnt    = (int*)alloc((size_t)(NB + 1) * 4);
    int*   boff    = (int*)alloc((size_t)(NB + 1) * 4);
    int*   bcur    = (int*)alloc((size_t)(NB + 1) * 4);
    short* W1pH    = (short*)alloc(32768 * 2);
    short* W1pL    = (short*)alloc(32768 * 2);
    short* W2pH    = (short*)alloc(16384 * 2);
    short* W2pL    = (short*)alloc(16384 * 2);
    int*   col     = (int*)alloc((size_t)E * 4);
    uint32* xb     = (uint32*)alloc((size_t)Np * 64 * 4);   // 25.6 MB
    float*  hr     = (float*)alloc((size_t)Np * 64 * 4);    // 25.6 MB
    unsigned short* hl = (unsigned short*)alloc((size_t)N * 64 * 2);  // 12.8 MB
    // alias (lifetime-disjoint): eb dead after k_bfinal; hl written by k_fused
    uint32* eb = (uint32*)hl;

    hipMemsetAsync(bcnt, 0, (size_t)NB * 4, stream);
    long n4 = (long)N * 32;
    long prep_items = n4 + 32768 + 16384;
    k_prep<<<(int)((prep_items + 255) / 256), 256, 0, stream>>>(
        x, xb, n4, W1l, W1r, W2l, W2r, W1pH, W1pL, W2pH, W2pL);
    k_bcount<<<256, 256, 0, stream>>>(ei, E, NB, bcnt);
    k_bscan<<<1, 1024, 0, stream>>>(bcnt, NB, E, boff, bcur);
    k_bscatter<<<128, 256, 0, stream>>>(ei, E, NB, bcur, eb);
    k_bfinal<<<NB, 256, 0, stream>>>(eb, boff, row_ptr, col, N, E);

    k_fused<<<mb, 256, 0, stream>>>(row_ptr, col, xb, W1pH, W1pL, W2pH, W2pL,
                                    b1, b2, hl, hr, N);
    int ab = (N + 7) / 8;
    k_agg_out<<<ab, 256, 0, stream>>>(row_ptr, col, hl, hr, out, N);
}